// Round 18
// baseline (414.039 us; speedup 1.0000x reference)
//
#include <hip/hip_runtime.h>
#include <hip/hip_bf16.h>
#include <math.h>

typedef __attribute__((ext_vector_type(8))) _Float16 half8;
typedef __attribute__((ext_vector_type(4))) float f32x4;
typedef unsigned short u16;
typedef unsigned int u32;

// ---------- helpers ----------
__device__ __forceinline__ u16 f2h(float f) {
    union { _Float16 h; u16 u; } c; c.h = (_Float16)f; return c.u;
}
__device__ __forceinline__ float h2f(u16 u) {
    union { u16 u; _Float16 h; } c; c.u = u; return (float)c.h;
}
__device__ __forceinline__ float bf2f(u16 u) {
    union { u32 i; float f; } x; x.i = ((u32)u) << 16; return x.f;
}
__device__ __forceinline__ u16 f2bf(float f) {
    union { float f; u32 i; } u; u.f = f;
    u32 r = u.i + 0x7fffu + ((u.i >> 16) & 1u);   // RNE
    return (u16)(r >> 16);
}
__device__ __forceinline__ float dotpair(u32 a, u32 b) {
    union { u32 i; float f; } alo, ahi, blo, bhi;
    alo.i = a << 16; ahi.i = a & 0xffff0000u;
    blo.i = b << 16; bhi.i = b & 0xffff0000u;
    return alo.f * blo.f + ahi.f * bhi.f;
}
// swizzled W layout: fragment-major; lane reads frag at ((wslot*4+ks)*512 + kg*128 + lr*8)
__device__ __forceinline__ int swz_idx(int m, int k) {
    return ((((m >> 4) * 4 + (k >> 5)) * 4 + ((k >> 3) & 3)) * 16 + (m & 15)) * 8 + (k & 7);
}

// ---------- batched weight prep (writes swizzled f16 hi/lo) ----------
struct TJob { const float* src; u16* hi; u16* lo; int M; };
struct TJobs { TJob j[10]; };

__global__ void prep_wt_all_k(TJobs jobs) {
    TJob t = jobs.j[blockIdx.y];
    int idx = blockIdx.x * 256 + threadIdx.x;
    if (idx >= t.M * 128) return;
    int m = idx >> 7, k = idx & 127;
    float w = t.src[k * t.M + m];
    u16 h = f2h(w);
    int o = swz_idx(m, k);
    t.hi[o] = h;
    t.lo[o] = f2h(w - h2f(h));
}

// fused (w @ blockdiag(rel)) -> WQ[l][kv] / WA[l][kv] chunks (swizzled f16)
__global__ void prep_fused_k(const float* kw_q, const float* kw_a,
                             const float* vw_q, const float* vw_a,
                             const float* a_rel, const float* m_rel,
                             u16* WQh, u16* WQl, u16* WAh, u16* WAl) {
    int j = blockIdx.y;
    int l = j >> 2, dir = (j >> 1) & 1, kv = j & 1;
    const float* w = kv ? (dir ? vw_a : vw_q) : (dir ? kw_a : kw_q);
    w += l * 16384;
    const float* rel = (kv ? m_rel : a_rel) + (l * 2 + dir) * 2048;
    u16* dhi = (dir ? WAh : WQh) + (l * 3 + kv) * 16384;
    u16* dlo = (dir ? WAl : WQl) + (l * 3 + kv) * 16384;
    int idx = blockIdx.x * 256 + threadIdx.x;       // 16384
    int m = idx >> 7, k = idx & 127;
    int h = m >> 4, f = m & 15;
    float s = 0.f;
#pragma unroll
    for (int d = 0; d < 16; d++)
        s += w[k * 128 + h * 16 + d] * rel[(h * 16 + d) * 16 + f];
    u16 hh = f2h(s);
    int o = swz_idx(m, k);
    dhi[o] = hh;
    dlo[o] = f2h(s - h2f(hh));
}

// BQ[2][384], BA[2][384] (f32): [fused kb | fused vb | qb]
__global__ void prep_bias_k(const float* kb_q, const float* vb_q, const float* qb_q,
                            const float* kb_a, const float* vb_a, const float* qb_a,
                            const float* a_rel, const float* m_rel,
                            float* BQ, float* BA) {
    int idx = blockIdx.x * 256 + threadIdx.x;
    if (idx >= 1536) return;
    int side = idx / 768, r = idx % 768;
    int l = r / 384, m = r % 384;
    float* dst = side ? BA : BQ;
    if (m >= 256) {
        const float* qb = side ? qb_a : qb_q;
        dst[l * 384 + m] = qb[l * 128 + (m - 256)];
        return;
    }
    int kv = m >> 7, mc = m & 127, h = mc >> 4, f = mc & 15;
    const float* b = side ? (kv ? vb_a : kb_a) : (kv ? vb_q : kb_q);
    b += l * 128;
    const float* rel = (kv ? m_rel : a_rel) + (l * 2 + side) * 2048;
    float s = 0.f;
#pragma unroll
    for (int d = 0; d < 16; d++) s += b[h * 16 + d] * rel[(h * 16 + d) * 16 + f];
    dst[l * 384 + m] = s;
}

// fused output-layer weights: per side, W1 = g*aw[1]@Wlin, W2 = (1-g)*Wlin,
// bO = g*(ab[1]@Wlin) + lin_b   (g = sigmoid(skip[1]), device data)
__global__ void prep_out_k(const float* aw_q, const float* ab_q, const float* skip_q,
                           const float* aw_a, const float* ab_a, const float* skip_a,
                           const float* lin_w, const float* lin_b,
                           u16* W1h, u16* W1l, u16* W2h, u16* W2l, float* bO) {
    int side = blockIdx.y;
    const float* aw = (side ? aw_a : aw_q) + 16384;   // layer 1
    const float* ab = (side ? ab_a : ab_q) + 128;
    float gk = (side ? skip_a : skip_q)[1];
    float g = 1.f / (1.f + __expf(-gk));
    int idx = blockIdx.x * 256 + threadIdx.x;         // 8192 = 128*64
    if (idx >= 8192) return;
    int k = idx >> 6, m = idx & 63;
    float s = 0.f;
#pragma unroll 4
    for (int d = 0; d < 128; d++) s += aw[k * 128 + d] * lin_w[d * 64 + m];
    s *= g;
    int o = swz_idx(m, k);
    u16 hh = f2h(s);
    W1h[side * 8192 + o] = hh;
    W1l[side * 8192 + o] = f2h(s - h2f(hh));
    float w2 = (1.f - g) * lin_w[k * 64 + m];
    u16 h2v = f2h(w2);
    W2h[side * 8192 + o] = h2v;
    W2l[side * 8192 + o] = f2h(w2 - h2f(h2v));
    if (k == 0) {
        float b = 0.f;
#pragma unroll 4
        for (int d = 0; d < 128; d++) b += ab[d] * lin_w[d * 64 + m];
        bO[side * 64 + m] = g * b + lin_b[m];
    }
}

// ---------- batched CSR build (y = edge-set index) ----------
__global__ void hist2_k(const int* dA, int Ea, int* degA,
                        const int* dB, int Eb, int* degB) {
    int y = blockIdx.y;
    const int* dst = y ? dB : dA; int E = y ? Eb : Ea; int* deg = y ? degB : degA;
    int i = blockIdx.x * 256 + threadIdx.x;
    if (i < E) atomicAdd(&deg[dst[i]], 1);
}
__global__ void scanA2_k(const int* degA, int* inclA, int* bsumA, int nA,
                         const int* degB, int* inclB, int* bsumB, int nB) {
    int y = blockIdx.y;
    const int* deg = y ? degB : degA; int* incl = y ? inclB : inclA;
    int* bsum = y ? bsumB : bsumA; int n = y ? nB : nA;
    __shared__ int s[256];
    int i = blockIdx.x * 256 + threadIdx.x;
    int v = (i < n) ? deg[i] : 0;
    s[threadIdx.x] = v;
    __syncthreads();
    for (int off = 1; off < 256; off <<= 1) {
        int t = (threadIdx.x >= off) ? s[threadIdx.x - off] : 0;
        __syncthreads();
        s[threadIdx.x] += t;
        __syncthreads();
    }
    if (i < n) incl[i] = s[threadIdx.x];
    if (threadIdx.x == 255) bsum[blockIdx.x] = s[255];
}
__global__ void scanB2_k(int* bsumA, int nbA, int* bsumB, int nbB) {
    int* bsum = blockIdx.x ? bsumB : bsumA;
    int nb = blockIdx.x ? nbB : nbA;
    __shared__ int s[256];
    int v = (threadIdx.x < nb) ? bsum[threadIdx.x] : 0;
    s[threadIdx.x] = v;
    __syncthreads();
    for (int off = 1; off < 256; off <<= 1) {
        int t = (threadIdx.x >= off) ? s[threadIdx.x - off] : 0;
        __syncthreads();
        s[threadIdx.x] += t;
        __syncthreads();
    }
    if (threadIdx.x < nb) bsum[threadIdx.x] = s[threadIdx.x] - v;  // exclusive
}
__global__ void scanC2_k(const int* inclA, const int* degA, const int* bsumA,
                         int* offsA, int* curA, int nA, int Ea,
                         const int* inclB, const int* degB, const int* bsumB,
                         int* offsB, int* curB, int nB, int Eb) {
    int y = blockIdx.y;
    const int* incl = y ? inclB : inclA; const int* deg = y ? degB : degA;
    const int* bsum = y ? bsumB : bsumA;
    int* offs = y ? offsB : offsA; int* cur = y ? curB : curA;
    int n = y ? nB : nA; int E = y ? Eb : Ea;
    int i = blockIdx.x * 256 + threadIdx.x;
    if (i < n) {
        int o = incl[i] - deg[i] + bsum[blockIdx.x];
        offs[i] = o;
        cur[i] = o;
    }
    if (i == 0) offs[n] = E;
}
__global__ void scatter2_k(const int* eiA, int Ea, int* curA, int* srccA,
                           const int* eiB, int Eb, int* curB, int* srccB) {
    int y = blockIdx.y;
    const int* ei = y ? eiB : eiA; int E = y ? Eb : Ea;
    int* cur = y ? curB : curA; int* srcc = y ? srccB : srccA;
    int e = blockIdx.x * 256 + threadIdx.x;
    if (e < E) {
        int p = atomicAdd(&cur[ei[E + e]], 1);   // dst row
        srcc[p] = ei[e];                          // src id in CSR order
    }
}

// ---------- fused edge phase: no-max softmax (den lane-local), single f16 msg plane ----------
struct EJob {
    const int* offs; const int* srcc;
    const u16* kt; const u16* vt; const u16* qd;
    const float* pr;
    u16* mhi; int n;
};
struct EJobs { EJob j[2]; };

__global__ __launch_bounds__(256) void edge_fused_k(EJobs jobs) {
    EJob J = jobs.j[blockIdx.y];
    int lane = threadIdx.x & 63;
    int node = blockIdx.x * 4 + (threadIdx.x >> 6);
    if (node >= J.n) return;
    int s0 = J.offs[node], s1 = J.offs[node + 1];
    int h = lane & 7, jj = lane >> 3;
    int hc = lane >> 3;                 // head of this lane's channel pair

    float accx = 0.f, accy = 0.f, den = 0.f;

    if (s0 < s1) {
        const u16* qrow = J.qd + (size_t)node * 128 + h * 16;
        uint4 q0 = *(const uint4*)qrow;
        uint4 q1 = *(const uint4*)(qrow + 8);
        float prh = J.pr[h] * 0.25f;    // SCALE = 1/sqrt(16)

        int jf = s0 + jj;
        int src_next = J.srcc[(jf < s1) ? jf : (s1 - 1)];
        for (int base = s0; base < s1; base += 8) {
            int cnt = s1 - base; if (cnt > 8) cnt = 8;
            int src = src_next;
            if (base + 8 < s1) {                    // prefetch next chunk's src ids
                int jn = base + 8 + jj;
                src_next = J.srcc[(jn < s1) ? jn : (s1 - 1)];
            }
            const u16* krow = J.kt + (size_t)src * 128 + h * 16;
            uint4 k0 = *(const uint4*)krow;
            uint4 k1 = *(const uint4*)(krow + 8);
            float a = dotpair(k0.x, q0.x) + dotpair(k0.y, q0.y)
                    + dotpair(k0.z, q0.z) + dotpair(k0.w, q0.w)
                    + dotpair(k1.x, q1.x) + dotpair(k1.y, q1.y)
                    + dotpair(k1.z, q1.z) + dotpair(k1.w, q1.w);
            float p = (jj < cnt) ? __expf(a * prh) : 0.f;
            den += p;                                // lane-local, reduced once at end

            u32 vv[8];
#pragma unroll
            for (int t = 0; t < 8; t++) {
                int s2 = __shfl(src, t * 8);
                vv[t] = (t < cnt) ? *(const u32*)(J.vt + (size_t)s2 * 128 + lane * 2) : 0u;
            }
#pragma unroll
            for (int t = 0; t < 8; t++) {
                float w = __shfl(p, t * 8 + hc);     // 0 for invalid lanes
                accx += w * bf2f((u16)(vv[t] & 0xffffu));
                accy += w * bf2f((u16)(vv[t] >> 16));
            }
        }
        den += __shfl_xor(den, 8);
        den += __shfl_xor(den, 16);
        den += __shfl_xor(den, 32);
    }

    float dc = __shfl(den, hc);
    float inv = (dc > 0.f) ? (1.f / dc) : 0.f;
    float vx = accx * inv, vy = accy * inv;
    vx = 0.5f * vx * (1.f + erff(vx * 0.70710678118654752f));
    vy = 0.5f * vy * (1.f + erff(vy * 0.70710678118654752f));
    size_t ob = (size_t)node * 128 + lane * 2;
    *(u32*)(J.mhi + ob) = (u32)f2h(vx) | ((u32)f2h(vy) << 16);
}

// ---------- register-W GEMM family (f16 MFMA) ----------

// projection: SINGLE-MFMA f16, THREE W chunks per job (A loaded once), 16-row tiles, 2 jobs
struct GJob3 { const u16* xhi; const u16* wh; const float* bias;
               u16* y0; u16* y1; u16* y2; int N; };
struct GJobs3 { GJob3 j[2]; };

__global__ __launch_bounds__(256, 3) void gemm_proj3_k(GJobs3 jobs) {
    GJob3 J = jobs.j[blockIdx.y];
    int tid = threadIdx.x;
    int wave = tid >> 6, lane = tid & 63;
    int lr = lane & 15, kg = lane >> 4;
    u16* const ys[3] = {J.y0, J.y1, J.y2};

    half8 wh[3][2][4];
#pragma unroll
    for (int c = 0; c < 3; c++)
#pragma unroll
        for (int ct = 0; ct < 2; ct++)
#pragma unroll
            for (int ks = 0; ks < 4; ks++) {
                int o = c * 16384 + ((wave * 2 + ct) * 4 + ks) * 512 + kg * 128 + lr * 8;
                wh[c][ct][ks] = *(const half8*)(J.wh + o);
            }

    int N = J.N;
    int ntiles = (N + 15) >> 4;
    for (int t = blockIdx.x; t < ntiles; t += gridDim.x) {
        int arow = t * 16 + lr;
        if (arow >= N) arow = N - 1;
        const u16* ph = J.xhi + (size_t)arow * 128 + kg * 8;
        half8 ah[4];
#pragma unroll
        for (int ks = 0; ks < 4; ks++) ah[ks] = *(const half8*)(ph + ks * 32);

        int crow0 = t * 16 + kg * 4;
#pragma unroll
        for (int c = 0; c < 3; c++) {
            f32x4 acc[2] = {f32x4{0.f, 0.f, 0.f, 0.f}, f32x4{0.f, 0.f, 0.f, 0.f}};
#pragma unroll
            for (int ks = 0; ks < 4; ks++)
#pragma unroll
                for (int ct = 0; ct < 2; ct++)
                    acc[ct] = __builtin_amdgcn_mfma_f32_16x16x32_f16(ah[ks], wh[c][ct][ks], acc[ct], 0, 0, 0);
#pragma unroll
            for (int ct = 0; ct < 2; ct++) {
                int col = (wave * 2 + ct) * 16 + lr;
                float bcol = J.bias[c * 128 + col];
#pragma unroll
                for (int r = 0; r < 4; r++) {
                    int gr = crow0 + r;
                    if (gr < N) ys[c][(size_t)gr * 128 + col] = f2bf(acc[ct][r] + bcol);
                }
            }
        }
    }
}

// skip GEMM: single-plane f16 msg -> gated mix with single-plane f16 x (in place), 2 jobs
struct SJob { const u16* mhi; const u16* wh; const u16* wl;
              const float* bias; u16* xhi; const float* gate; int N; };
struct SJobs { SJob j[2]; };

__global__ __launch_bounds__(256, 4) void gemm_skip_k(SJobs jobs) {
    SJob J = jobs.j[blockIdx.y];
    int tid = threadIdx.x;
    int wave = tid >> 6, lane = tid & 63;
    int lr = lane & 15, kg = lane >> 4;

    half8 wh[2][4], wl[2][4];
#pragma unroll
    for (int ct = 0; ct < 2; ct++)
#pragma unroll
        for (int ks = 0; ks < 4; ks++) {
            int o = ((wave * 2 + ct) * 4 + ks) * 512 + kg * 128 + lr * 8;
            wh[ct][ks] = *(const half8*)(J.wh + o);
            wl[ct][ks] = *(const half8*)(J.wl + o);
        }
    float gk = J.gate[0];
    float g = 1.f / (1.f + __expf(-gk));
    float gi = 1.f - g;

    int ntiles = (J.N + 15) >> 4;
    for (int t = blockIdx.x; t < ntiles; t += gridDim.x) {
        int arow = t * 16 + lr;
        if (arow >= J.N) arow = J.N - 1;
        const u16* ph = J.mhi + (size_t)arow * 128 + kg * 8;
        half8 ah[4];
#pragma unroll
        for (int ks = 0; ks < 4; ks++) ah[ks] = *(const half8*)(ph + ks * 32);
        f32x4 acc[2] = {f32x4{0.f, 0.f, 0.f, 0.f}, f32x4{0.f, 0.f, 0.f, 0.f}};
#pragma unroll
        for (int ks = 0; ks < 4; ks++)
#pragma unroll
            for (int ct = 0; ct < 2; ct++) {
                acc[ct] = __builtin_amdgcn_mfma_f32_16x16x32_f16(ah[ks], wh[ct][ks], acc[ct], 0, 0, 0);
                acc[ct] = __builtin_amdgcn_mfma_f32_16x16x32_f16(ah[ks], wl[ct][ks], acc[ct], 0, 0, 0);
            }
        int crow0 = t * 16 + kg * 4;
#pragma unroll
        for (int ct = 0; ct < 2; ct++) {
            int col = (wave * 2 + ct) * 16 + lr;
            float bcol = J.bias[col];
#pragma unroll
            for (int r = 0; r < 4; r++) {
                int gr = crow0 + r;
                if (gr < J.N) {
                    size_t si = (size_t)gr * 128 + col;
                    float v = acc[ct][r] + bcol;
                    v = g * v + gi * h2f(J.xhi[si]);
                    J.xhi[si] = f2h(v);
                }
            }
        }
    }
}

// input projection: f32 A + relu -> single f16 plane, 2 jobs (value via full split math)
struct FJob { const float* x; const u16* wh; const u16* wl; const float* bias;
              u16* yhi; int N; };
struct FJobs { FJob j[2]; };

__global__ __launch_bounds__(256, 3) void gemm_in_k(FJobs jobs) {
    FJob J = jobs.j[blockIdx.y];
    int tid = threadIdx.x;
    int wave = tid >> 6, lane = tid & 63;
    int lr = lane & 15, kg = lane >> 4;

    half8 wh[2][4], wl[2][4];
#pragma unroll
    for (int ct = 0; ct < 2; ct++)
#pragma unroll
        for (int ks = 0; ks < 4; ks++) {
            int o = ((wave * 2 + ct) * 4 + ks) * 512 + kg * 128 + lr * 8;
            wh[ct][ks] = *(const half8*)(J.wh + o);
            wl[ct][ks] = *(const half8*)(J.wl + o);
        }

    int ntiles = (J.N + 15) >> 4;
    for (int t = blockIdx.x; t < ntiles; t += gridDim.x) {
        int arow = t * 16 + lr;
        if (arow >= J.N) arow = J.N - 1;
        const float* p = J.x + (size_t)arow * 128 + kg * 8;
        half8 ahi[4], alo[4];
#pragma unroll
        for (int ks = 0; ks < 4; ks++) {
            float4 v0 = *(const float4*)(p + ks * 32);
            float4 v1 = *(const float4*)(p + ks * 32 + 4);
            float a8[8] = {v0.x, v0.y, v0.z, v0.w, v1.x, v1.y, v1.z, v1.w};
#pragma unroll
            for (int j = 0; j < 8; j++) {
                _Float16 h = (_Float16)a8[j];
                ahi[ks][j] = h;
                alo[ks][j] = (_Float16)(a8[j] - (float)h);
            }
        }
        f32x4 acc[2] = {f32x4{0.f, 0.f, 0.f, 0.f}, f32x4{0.f, 0.f, 0.f, 0.f}};
#pragma unroll
        for (int ks = 0; ks < 4; ks++)
#pragma unroll
            for (int ct = 0; ct < 2; ct++) {
                acc[ct] = __builtin_amdgcn_mfma_f32_16x16x32_f16(ahi[ks], wh[ct][ks], acc[ct], 0, 0, 0);
                acc[ct] = __builtin_amdgcn_mfma_f32_16x16x32_f16(alo[ks], wh[ct][ks], acc[ct], 0, 0, 0);
                acc[ct] = __builtin_amdgcn_mfma_f32_16x16x32_f16(ahi[ks], wl[ct][ks], acc[ct], 0, 0, 0);
            }
        int crow0 = t * 16 + kg * 4;
#pragma unroll
        for (int ct = 0; ct < 2; ct++) {
            int col = (wave * 2 + ct) * 16 + lr;
            float bcol = J.bias[col];
#pragma unroll
            for (int r = 0; r < 4; r++) {
                int gr = crow0 + r;
                if (gr < J.N) {
                    float v = fmaxf(acc[ct][r] + bcol, 0.f);
                    J.yhi[(size_t)gr * 128 + col] = f2h(v);
                }
            }
        }
    }
}

// fused output: out = msg @ W1 + x @ W2 + bO   (f32 out, MOUT=64), 2 jobs
struct OJob { const u16* mhi; const u16* xhi;
              const u16* w1h; const u16* w1l; const u16* w2h; const u16* w2l;
              const float* bO; float* out; int N; };
struct OJobs { OJob j[2]; };

__global__ __launch_bounds__(256, 4) void gemm_out_k(OJobs jobs) {
    OJob J = jobs.j[blockIdx.y];
    int tid = threadIdx.x;
    int wave = tid >> 6, lane = tid & 63;
    int lr = lane & 15, kg = lane >> 4;

    half8 w1h[4], w1l[4], w2h[4], w2l[4];
#pragma unroll
    for (int ks = 0; ks < 4; ks++) {
        int o = (wave * 4 + ks) * 512 + kg * 128 + lr * 8;
        w1h[ks] = *(const half8*)(J.w1h + o);
        w1l[ks] = *(const half8*)(J.w1l + o);
        w2h[ks] = *(const half8*)(J.w2h + o);
        w2l[ks] = *(const half8*)(J.w2l + o);
    }

    int N = J.N;
    int ntiles = (N + 15) >> 4;
    for (int t = blockIdx.x; t < ntiles; t += gridDim.x) {
        int arow = t * 16 + lr;
        if (arow >= N) arow = N - 1;
        const u16* pm = J.mhi + (size_t)arow * 128 + kg * 8;
        const u16* px = J.xhi + (size_t)arow * 128 + kg * 8;
        half8 am[4], ax[4];
#pragma unroll
        for (int ks = 0; ks < 4; ks++) {
            am[ks] = *(const half8*)(pm + ks * 32);
            ax[ks] = *(const half8*)(px + ks * 32);
        }
        f32x4 acc = f32x4{0.f, 0.f, 0.f, 0.f};
#pragma unroll
        for (int ks = 0; ks < 4; ks++) {
            acc = __builtin_amdgcn_mfma_f32_16x16x32_f16(am[ks], w1h[ks], acc, 0, 0, 0);
            acc = __builtin_amdgcn_mfma_f32_16x16x32_f16(am[ks], w1l[ks], acc, 0, 0, 0);
            acc = __builtin_amdgcn_mfma_f32_16x16x32_f16(ax[ks], w2h[ks], acc, 0, 0, 0);
            acc = __builtin_amdgcn_mfma_f32_16x16x32_f16(ax[ks], w2l[ks], acc, 0, 0, 0);
        }
        int crow0 = t * 16 + kg * 4;
        int col = wave * 16 + lr;
        float bcol = J.bO[col];
#pragma unroll
        for (int r = 0; r < 4; r++) {
            int gr = crow0 + r;
            if (gr < N) J.out[(size_t)gr * 64 + col] = acc[r] + bcol;
        }
    }
}

// ---------- launch ----------
extern "C" void kernel_launch(void* const* d_in, const int* in_sizes, int n_in,
                              void* d_out, int out_size, void* d_ws, size_t ws_size,
                              hipStream_t stream) {
    const int NQ = in_sizes[0] / 128;
    const int NA = in_sizes[1] / 128;
    const int Eqa = in_sizes[29] / 2;
    const int Eaq = in_sizes[30] / 2;
    const int NM = (NQ > NA) ? NQ : NA;
    const int EM = (Eqa > Eaq) ? Eqa : Eaq;

    const float* x_q     = (const float*)d_in[0];
    const float* x_a     = (const float*)d_in[1];
    const float* lin0_wq = (const float*)d_in[2];
    const float* lin0_bq = (const float*)d_in[3];
    const float* lin0_wa = (const float*)d_in[4];
    const float* lin0_ba = (const float*)d_in[5];
    const float* kw_q = (const float*)d_in[6];
    const float* kb_q = (const float*)d_in[7];
    const float* qw_q = (const float*)d_in[8];
    const float* qb_q = (const float*)d_in[9];
    const float* vw_q = (const float*)d_in[10];
    const float* vb_q = (const float*)d_in[11];
    const float* aw_q = (const float*)d_in[12];
    const float* ab_q = (const float*)d_in[13];
    const float* kw_a = (const float*)d_in[14];
    const float* kb_a = (const float*)d_in[15];
    const float* qw_a = (const float*)d_in[16];
    const float* qb_a = (const float*)d_in[17];
    const float* vw_a = (const float*)d_in[18];
    const float* vb_a = (const float*)d_in[19];
    const float* aw_a = (const float*)d_in[20];
    const float* ab_a = (const float*)d_in[21];
    const float* skip_q = (const float*)d_in[22];
    const float* skip_a = (const float*)d_in[23];
    const float* a_rel = (const float*)d_in[24];
    const float* m_rel = (const float*)d_in[25];
    const float* p_rel = (const float*)d_in[26];
    const float* lin_w = (const float*)d_in[27];
    const float* lin_b = (const float*)d_in[28];
    const int* ei_qa = (const int*)d_in[29];
    const int* ei_aq = (const int*)d_in[30];

    // ---- workspace ----
    size_t off = 0;
    auto alloc = [&](size_t bytes) -> void* {
        void* p = (char*)d_ws + off;
        off += (bytes + 255) & ~(size_t)255;
        return p;
    };
    u16* xhi = (u16*)alloc((size_t)(NQ + NA) * 128 * 2);   // rows [0,NQ)=q, rest=a
    u16* xq_hi = xhi;
    u16* xa_hi = xhi + (size_t)NQ * 128;
    u16* mq_hi = (u16*)alloc((size_t)NQ * 128 * 2);
    u16* ma_hi = (u16*)alloc((size_t)NA * 128 * 2);
    u16* kt0 = (u16*)alloc((size_t)NM * 128 * 2);
    u16* vt0 = (u16*)alloc((size_t)NM * 128 * 2);
    u16* qdq = (u16*)alloc((size_t)NM * 128 * 2);
    u16* kt1 = (u16*)alloc((size_t)NM * 128 * 2);
    u16* vt1 = (u16*)alloc((size_t)NM * 128 * 2);
    u16* qda = (u16*)alloc((size_t)NM * 128 * 2);
    int* offs_a = (int*)alloc((size_t)(NA + 1) * 4);
    int* offs_q = (int*)alloc((size_t)(NQ + 1) * 4);
    int* srcc_a = (int*)alloc((size_t)Eqa * 4);
    int* srcc_q = (int*)alloc((size_t)Eaq * 4);
    int* deg    = (int*)alloc((size_t)2 * NM * 4);
    int* cursor = (int*)alloc((size_t)2 * NM * 4);
    int* incl   = (int*)alloc((size_t)2 * NM * 4);
    int* bsum   = (int*)alloc(2048);
    u16* W_LIN0Q_h = (u16*)alloc(16384 * 2); u16* W_LIN0Q_l = (u16*)alloc(16384 * 2);
    u16* W_LIN0A_h = (u16*)alloc(16384 * 2); u16* W_LIN0A_l = (u16*)alloc(16384 * 2);
    u16* WQ_h = (u16*)alloc(2 * 3 * 16384 * 2); u16* WQ_l = (u16*)alloc(2 * 3 * 16384 * 2);
    u16* WA_h = (u16*)alloc(2 * 3 * 16384 * 2); u16* WA_l = (u16*)alloc(2 * 3 * 16384 * 2);
    u16* W_AQ_h = (u16*)alloc(2 * 16384 * 2); u16* W_AQ_l = (u16*)alloc(2 * 16384 * 2);
    u16* W_AA_h = (u16*)alloc(2 * 16384 * 2); u16* W_AA_l = (u16*)alloc(2 * 16384 * 2);
    u16* W1h = (u16*)alloc(2 * 8192 * 2); u16* W1l = (u16*)alloc(2 * 8192 * 2);
    u16* W2h = (u16*)alloc(2 * 8192 * 2); u16* W2l = (u16*)alloc(2 * 8192 * 2);
    float* bO = (float*)alloc(2 * 64 * 4);
    float* BQ = (float*)alloc(2 * 384 * 4);
    float* BA = (float*)alloc(2 * 384 * 4);
    (void)ws_size; (void)n_in; (void)out_size; (void)EM;

    dim3 B(256);

    // weight prep
    TJobs tj;
    tj.j[0]  = {lin0_wq, W_LIN0Q_h, W_LIN0Q_l, 128};
    tj.j[1]  = {lin0_wa, W_LIN0A_h, W_LIN0A_l, 128};
    tj.j[2]  = {qw_q,          WQ_h + (0 * 3 + 2) * 16384, WQ_l + (0 * 3 + 2) * 16384, 128};
    tj.j[3]  = {qw_q + 16384,  WQ_h + (1 * 3 + 2) * 16384, WQ_l + (1 * 3 + 2) * 16384, 128};
    tj.j[4]  = {qw_a,          WA_h + (0 * 3 + 2) * 16384, WA_l + (0 * 3 + 2) * 16384, 128};
    tj.j[5]  = {qw_a + 16384,  WA_h + (1 * 3 + 2) * 16384, WA_l + (1 * 3 + 2) * 16384, 128};
    tj.j[6]  = {aw_q,          W_AQ_h,            W_AQ_l,            128};
    tj.j[7]  = {aw_q + 16384,  W_AQ_h + 16384,    W_AQ_l + 16384,    128};
    tj.j[8]  = {aw_a,          W_AA_h,            W_AA_l,            128};
    tj.j[9]  = {aw_a + 16384,  W_AA_h + 16384,    W_AA_l + 16384,    128};
    prep_wt_all_k<<<dim3(64, 10), B, 0, stream>>>(tj);
    prep_fused_k<<<dim3(64, 8), B, 0, stream>>>(kw_q, kw_a, vw_q, vw_a, a_rel, m_rel,
                                                WQ_h, WQ_l, WA_h, WA_l);
    prep_bias_k<<<dim3(6), B, 0, stream>>>(kb_q, vb_q, qb_q, kb_a, vb_a, qb_a,
                                           a_rel, m_rel, BQ, BA);
    prep_out_k<<<dim3(32, 2), B, 0, stream>>>(aw_q, ab_q, skip_q, aw_a, ab_a, skip_a,
                                              lin_w, lin_b, W1h, W1l, W2h, W2l, bO);

    // CSR build
    int* degA = deg;        int* degB = deg + NM;
    int* curA = cursor;     int* curB = cursor + NM;
    int* incA = incl;       int* incB = incl + NM;
    int* bsA  = bsum;       int* bsB  = bsum + 256;
    int gEm = (EM + 255) / 256, gNm = (NM + 255) / 256;
    int gNa = (NA + 255) / 256, gNq = (NQ + 255) / 256;
    hipMemsetAsync(deg, 0, (size_t)2 * NM * 4, stream);
    hist2_k<<<dim3(gEm, 2), B, 0, stream>>>(ei_qa + Eqa, Eqa, degA, ei_aq + Eaq, Eaq, degB);
    scanA2_k<<<dim3(gNm, 2), B, 0, stream>>>(degA, incA, bsA, NA, degB, incB, bsB, NQ);
    scanB2_k<<<dim3(2), B, 0, stream>>>(bsA, gNa, bsB, gNq);
    scanC2_k<<<dim3(gNm, 2), B, 0, stream>>>(incA, degA, bsA, offs_a, curA, NA, Eqa,
                                             incB, degB, bsB, offs_q, curB, NQ, Eaq);
    scatter2_k<<<dim3(gEm, 2), B, 0, stream>>>(ei_qa, Eqa, curA, srcc_a,
                                               ei_aq, Eaq, curB, srcc_q);

    // input projections + relu -> single f16 plane (one dispatch, 2 jobs)
    {
        FJobs fj;
        fj.j[0] = {x_q, W_LIN0Q_h, W_LIN0Q_l, lin0_bq, xq_hi, NQ};
        fj.j[1] = {x_a, W_LIN0A_h, W_LIN0A_l, lin0_ba, xa_hi, NA};
        gemm_in_k<<<dim3(512, 2), B, 0, stream>>>(fj);
    }

    for (int l = 0; l < 2; l++) {
        // per side: one job computes kt|vt|qd (A read once, 3 W slices)
        GJobs3 gj;
        gj.j[0] = {xq_hi, WQ_h + l * 3 * 16384, BQ + l * 384, kt0, vt0, qdq, NQ};
        gj.j[1] = {xa_hi, WA_h + l * 3 * 16384, BA + l * 384, kt1, vt1, qda, NA};
        gemm_proj3_k<<<dim3(512, 2), B, 0, stream>>>(gj);

        // both edge directions in one dispatch (bf16 kt/vt/qd -> single f16 msg plane)
        EJobs ej;
        ej.j[0] = {offs_a, srcc_a, kt0, vt0, qda, p_rel + (l * 2 + 0) * 8, ma_hi, NA};
        ej.j[1] = {offs_q, srcc_q, kt1, vt1, qdq, p_rel + (l * 2 + 1) * 8, mq_hi, NQ};
        edge_fused_k<<<dim3((NM + 3) / 4, 2), B, 0, stream>>>(ej);

        if (l == 0) {
            // layer-0 skip (in-place on single x plane)
            SJobs sj;
            sj.j[0] = {mq_hi, W_AQ_h, W_AQ_l, ab_q, xq_hi, skip_q, NQ};
            sj.j[1] = {ma_hi, W_AA_h, W_AA_l, ab_a, xa_hi, skip_a, NA};
            gemm_skip_k<<<dim3(512, 2), B, 0, stream>>>(sj);
        } else {
            // layer-1 skip folded into final linear: out = msg@W1 + x1@W2 + bO
            OJobs oj;
            oj.j[0] = {mq_hi, xq_hi, W1h, W1l, W2h, W2l, bO,
                       (float*)d_out, NQ};
            oj.j[1] = {ma_hi, xa_hi, W1h + 8192, W1l + 8192, W2h + 8192, W2l + 8192, bO + 64,
                       (float*)d_out + (size_t)NQ * 64, NA};
            gemm_out_k<<<dim3(512, 2), B, 0, stream>>>(oj);
        }
    }
}

// Round 19
// 408.741 us; speedup vs baseline: 1.0130x; 1.0130x over previous
//
#include <hip/hip_runtime.h>
#include <hip/hip_bf16.h>
#include <math.h>

typedef __attribute__((ext_vector_type(8))) _Float16 half8;
typedef __attribute__((ext_vector_type(4))) float f32x4;
typedef unsigned short u16;
typedef unsigned int u32;

// ---------- helpers ----------
__device__ __forceinline__ u16 f2h(float f) {
    union { _Float16 h; u16 u; } c; c.h = (_Float16)f; return c.u;
}
__device__ __forceinline__ float h2f(u16 u) {
    union { u16 u; _Float16 h; } c; c.u = u; return (float)c.h;
}
__device__ __forceinline__ float bf2f(u16 u) {
    union { u32 i; float f; } x; x.i = ((u32)u) << 16; return x.f;
}
__device__ __forceinline__ u16 f2bf(float f) {
    union { float f; u32 i; } u; u.f = f;
    u32 r = u.i + 0x7fffu + ((u.i >> 16) & 1u);   // RNE
    return (u16)(r >> 16);
}
__device__ __forceinline__ float dotpair(u32 a, u32 b) {
    union { u32 i; float f; } alo, ahi, blo, bhi;
    alo.i = a << 16; ahi.i = a & 0xffff0000u;
    blo.i = b << 16; bhi.i = b & 0xffff0000u;
    return alo.f * blo.f + ahi.f * bhi.f;
}
// swizzled W layout: fragment-major; lane reads frag at ((wslot*4+ks)*512 + kg*128 + lr*8)
__device__ __forceinline__ int swz_idx(int m, int k) {
    return ((((m >> 4) * 4 + (k >> 5)) * 4 + ((k >> 3) & 3)) * 16 + (m & 15)) * 8 + (k & 7);
}

// ---------- merged weight prep: y<10 = plain transpose jobs, y>=10 = fused rel jobs ----------
struct TJob { const float* src; u16* hi; u16* lo; int M; };
struct PrepArgs {
    TJob j[10];
    const float* kw_q; const float* kw_a; const float* vw_q; const float* vw_a;
    const float* a_rel; const float* m_rel;
    u16* WQh; u16* WQl; u16* WAh; u16* WAl;
};

__global__ void prep_all_k(PrepArgs A) {
    int y = blockIdx.y;
    int idx = blockIdx.x * 256 + threadIdx.x;
    if (y < 10) {
        TJob t = A.j[y];
        if (idx >= t.M * 128) return;
        int m = idx >> 7, k = idx & 127;
        float w = t.src[k * t.M + m];
        u16 h = f2h(w);
        int o = swz_idx(m, k);
        t.hi[o] = h;
        t.lo[o] = f2h(w - h2f(h));
        return;
    }
    int j = y - 10;
    int l = j >> 2, dir = (j >> 1) & 1, kv = j & 1;
    const float* w = kv ? (dir ? A.vw_a : A.vw_q) : (dir ? A.kw_a : A.kw_q);
    w += l * 16384;
    const float* rel = (kv ? A.m_rel : A.a_rel) + (l * 2 + dir) * 2048;
    u16* dhi = (dir ? A.WAh : A.WQh) + (l * 3 + kv) * 16384;
    u16* dlo = (dir ? A.WAl : A.WQl) + (l * 3 + kv) * 16384;
    int m = idx >> 7, k = idx & 127;
    int h = m >> 4, f = m & 15;
    float s = 0.f;
#pragma unroll
    for (int d = 0; d < 16; d++)
        s += w[k * 128 + h * 16 + d] * rel[(h * 16 + d) * 16 + f];
    u16 hh = f2h(s);
    int o = swz_idx(m, k);
    dhi[o] = hh;
    dlo[o] = f2h(s - h2f(hh));
}

// BQ[2][384], BA[2][384] (f32): [fused kb | fused vb | qb]
__global__ void prep_bias_k(const float* kb_q, const float* vb_q, const float* qb_q,
                            const float* kb_a, const float* vb_a, const float* qb_a,
                            const float* a_rel, const float* m_rel,
                            float* BQ, float* BA) {
    int idx = blockIdx.x * 256 + threadIdx.x;
    if (idx >= 1536) return;
    int side = idx / 768, r = idx % 768;
    int l = r / 384, m = r % 384;
    float* dst = side ? BA : BQ;
    if (m >= 256) {
        const float* qb = side ? qb_a : qb_q;
        dst[l * 384 + m] = qb[l * 128 + (m - 256)];
        return;
    }
    int kv = m >> 7, mc = m & 127, h = mc >> 4, f = mc & 15;
    const float* b = side ? (kv ? vb_a : kb_a) : (kv ? vb_q : kb_q);
    b += l * 128;
    const float* rel = (kv ? m_rel : a_rel) + (l * 2 + side) * 2048;
    float s = 0.f;
#pragma unroll
    for (int d = 0; d < 16; d++) s += b[h * 16 + d] * rel[(h * 16 + d) * 16 + f];
    dst[l * 384 + m] = s;
}

// fused output-layer weights: per side, W1 = g*aw[1]@Wlin, W2 = (1-g)*Wlin,
// bO = g*(ab[1]@Wlin) + lin_b   (g = sigmoid(skip[1]), device data)
__global__ void prep_out_k(const float* aw_q, const float* ab_q, const float* skip_q,
                           const float* aw_a, const float* ab_a, const float* skip_a,
                           const float* lin_w, const float* lin_b,
                           u16* W1h, u16* W1l, u16* W2h, u16* W2l, float* bO) {
    int side = blockIdx.y;
    const float* aw = (side ? aw_a : aw_q) + 16384;   // layer 1
    const float* ab = (side ? ab_a : ab_q) + 128;
    float gk = (side ? skip_a : skip_q)[1];
    float g = 1.f / (1.f + __expf(-gk));
    int idx = blockIdx.x * 256 + threadIdx.x;         // 8192 = 128*64
    if (idx >= 8192) return;
    int k = idx >> 6, m = idx & 63;
    float s = 0.f;
#pragma unroll 4
    for (int d = 0; d < 128; d++) s += aw[k * 128 + d] * lin_w[d * 64 + m];
    s *= g;
    int o = swz_idx(m, k);
    u16 hh = f2h(s);
    W1h[side * 8192 + o] = hh;
    W1l[side * 8192 + o] = f2h(s - h2f(hh));
    float w2 = (1.f - g) * lin_w[k * 64 + m];
    u16 h2v = f2h(w2);
    W2h[side * 8192 + o] = h2v;
    W2l[side * 8192 + o] = f2h(w2 - h2f(h2v));
    if (k == 0) {
        float b = 0.f;
#pragma unroll 4
        for (int d = 0; d < 128; d++) b += ab[d] * lin_w[d * 64 + m];
        bO[side * 64 + m] = g * b + lin_b[m];
    }
}

// ---------- batched CSR build (y = edge-set index) ----------
__global__ void hist2_k(const int* dA, int Ea, int* degA,
                        const int* dB, int Eb, int* degB) {
    int y = blockIdx.y;
    const int* dst = y ? dB : dA; int E = y ? Eb : Ea; int* deg = y ? degB : degA;
    int i = blockIdx.x * 256 + threadIdx.x;
    if (i < E) atomicAdd(&deg[dst[i]], 1);
}
__global__ void scanA2_k(const int* degA, int* inclA, int* bsumA, int nA,
                         const int* degB, int* inclB, int* bsumB, int nB) {
    int y = blockIdx.y;
    const int* deg = y ? degB : degA; int* incl = y ? inclB : inclA;
    int* bsum = y ? bsumB : bsumA; int n = y ? nB : nA;
    __shared__ int s[256];
    int i = blockIdx.x * 256 + threadIdx.x;
    int v = (i < n) ? deg[i] : 0;
    s[threadIdx.x] = v;
    __syncthreads();
    for (int off = 1; off < 256; off <<= 1) {
        int t = (threadIdx.x >= off) ? s[threadIdx.x - off] : 0;
        __syncthreads();
        s[threadIdx.x] += t;
        __syncthreads();
    }
    if (i < n) incl[i] = s[threadIdx.x];
    if (threadIdx.x == 255) bsum[blockIdx.x] = s[255];
}
__global__ void scanB2_k(int* bsumA, int nbA, int* bsumB, int nbB) {
    int* bsum = blockIdx.x ? bsumB : bsumA;
    int nb = blockIdx.x ? nbB : nbA;
    __shared__ int s[256];
    int v = (threadIdx.x < nb) ? bsum[threadIdx.x] : 0;
    s[threadIdx.x] = v;
    __syncthreads();
    for (int off = 1; off < 256; off <<= 1) {
        int t = (threadIdx.x >= off) ? s[threadIdx.x - off] : 0;
        __syncthreads();
        s[threadIdx.x] += t;
        __syncthreads();
    }
    if (threadIdx.x < nb) bsum[threadIdx.x] = s[threadIdx.x] - v;  // exclusive
}
__global__ void scanC2_k(const int* inclA, const int* degA, const int* bsumA,
                         int* offsA, int* curA, int nA, int Ea,
                         const int* inclB, const int* degB, const int* bsumB,
                         int* offsB, int* curB, int nB, int Eb) {
    int y = blockIdx.y;
    const int* incl = y ? inclB : inclA; const int* deg = y ? degB : degA;
    const int* bsum = y ? bsumB : bsumA;
    int* offs = y ? offsB : offsA; int* cur = y ? curB : curA;
    int n = y ? nB : nA; int E = y ? Eb : Ea;
    int i = blockIdx.x * 256 + threadIdx.x;
    if (i < n) {
        int o = incl[i] - deg[i] + bsum[blockIdx.x];
        offs[i] = o;
        cur[i] = o;
    }
    if (i == 0) offs[n] = E;
}
__global__ void scatter2_k(const int* eiA, int Ea, int* curA, int* srccA,
                           const int* eiB, int Eb, int* curB, int* srccB) {
    int y = blockIdx.y;
    const int* ei = y ? eiB : eiA; int E = y ? Eb : Ea;
    int* cur = y ? curB : curA; int* srcc = y ? srccB : srccA;
    int e = blockIdx.x * 256 + threadIdx.x;
    if (e < E) {
        int p = atomicAdd(&cur[ei[E + e]], 1);   // dst row
        srcc[p] = ei[e];                          // src id in CSR order
    }
}

// ---------- fused edge phase: no-max softmax (den lane-local), single f16 msg plane ----------
struct EJob {
    const int* offs; const int* srcc;
    const u16* kt; const u16* vt; const u16* qd;
    const float* pr;
    u16* mhi; int n;
};
struct EJobs { EJob j[2]; };

__global__ __launch_bounds__(256) void edge_fused_k(EJobs jobs) {
    EJob J = jobs.j[blockIdx.y];
    int lane = threadIdx.x & 63;
    int node = blockIdx.x * 4 + (threadIdx.x >> 6);
    if (node >= J.n) return;
    int s0 = J.offs[node], s1 = J.offs[node + 1];
    int h = lane & 7, jj = lane >> 3;
    int hc = lane >> 3;                 // head of this lane's channel pair

    float accx = 0.f, accy = 0.f, den = 0.f;

    if (s0 < s1) {
        const u16* qrow = J.qd + (size_t)node * 128 + h * 16;
        uint4 q0 = *(const uint4*)qrow;
        uint4 q1 = *(const uint4*)(qrow + 8);
        float prh = J.pr[h] * 0.25f;    // SCALE = 1/sqrt(16)

        int jf = s0 + jj;
        int src_next = J.srcc[(jf < s1) ? jf : (s1 - 1)];
        for (int base = s0; base < s1; base += 8) {
            int cnt = s1 - base; if (cnt > 8) cnt = 8;
            int src = src_next;
            if (base + 8 < s1) {                    // prefetch next chunk's src ids
                int jn = base + 8 + jj;
                src_next = J.srcc[(jn < s1) ? jn : (s1 - 1)];
            }
            const u16* krow = J.kt + (size_t)src * 128 + h * 16;
            uint4 k0 = *(const uint4*)krow;
            uint4 k1 = *(const uint4*)(krow + 8);
            float a = dotpair(k0.x, q0.x) + dotpair(k0.y, q0.y)
                    + dotpair(k0.z, q0.z) + dotpair(k0.w, q0.w)
                    + dotpair(k1.x, q1.x) + dotpair(k1.y, q1.y)
                    + dotpair(k1.z, q1.z) + dotpair(k1.w, q1.w);
            float p = (jj < cnt) ? __expf(a * prh) : 0.f;
            den += p;                                // lane-local, reduced once at end

            u32 vv[8];
#pragma unroll
            for (int t = 0; t < 8; t++) {
                int s2 = __shfl(src, t * 8);
                vv[t] = (t < cnt) ? *(const u32*)(J.vt + (size_t)s2 * 128 + lane * 2) : 0u;
            }
#pragma unroll
            for (int t = 0; t < 8; t++) {
                float w = __shfl(p, t * 8 + hc);     // 0 for invalid lanes
                accx += w * bf2f((u16)(vv[t] & 0xffffu));
                accy += w * bf2f((u16)(vv[t] >> 16));
            }
        }
        den += __shfl_xor(den, 8);
        den += __shfl_xor(den, 16);
        den += __shfl_xor(den, 32);
    }

    float dc = __shfl(den, hc);
    float inv = (dc > 0.f) ? (1.f / dc) : 0.f;
    float vx = accx * inv, vy = accy * inv;
    vx = 0.5f * vx * (1.f + erff(vx * 0.70710678118654752f));
    vy = 0.5f * vy * (1.f + erff(vy * 0.70710678118654752f));
    size_t ob = (size_t)node * 128 + lane * 2;
    *(u32*)(J.mhi + ob) = (u32)f2h(vx) | ((u32)f2h(vy) << 16);
}

// ---------- register-W GEMM family (f16 MFMA) ----------

// projection: SINGLE-MFMA f16, THREE W chunks per job (A loaded once), 16-row tiles, 2 jobs
struct GJob3 { const u16* xhi; const u16* wh; const float* bias;
               u16* y0; u16* y1; u16* y2; int N; };
struct GJobs3 { GJob3 j[2]; };

__global__ __launch_bounds__(256, 3) void gemm_proj3_k(GJobs3 jobs) {
    GJob3 J = jobs.j[blockIdx.y];
    int tid = threadIdx.x;
    int wave = tid >> 6, lane = tid & 63;
    int lr = lane & 15, kg = lane >> 4;
    u16* const ys[3] = {J.y0, J.y1, J.y2};

    half8 wh[3][2][4];
#pragma unroll
    for (int c = 0; c < 3; c++)
#pragma unroll
        for (int ct = 0; ct < 2; ct++)
#pragma unroll
            for (int ks = 0; ks < 4; ks++) {
                int o = c * 16384 + ((wave * 2 + ct) * 4 + ks) * 512 + kg * 128 + lr * 8;
                wh[c][ct][ks] = *(const half8*)(J.wh + o);
            }

    int N = J.N;
    int ntiles = (N + 15) >> 4;
    for (int t = blockIdx.x; t < ntiles; t += gridDim.x) {
        int arow = t * 16 + lr;
        if (arow >= N) arow = N - 1;
        const u16* ph = J.xhi + (size_t)arow * 128 + kg * 8;
        half8 ah[4];
#pragma unroll
        for (int ks = 0; ks < 4; ks++) ah[ks] = *(const half8*)(ph + ks * 32);

        int crow0 = t * 16 + kg * 4;
#pragma unroll
        for (int c = 0; c < 3; c++) {
            f32x4 acc[2] = {f32x4{0.f, 0.f, 0.f, 0.f}, f32x4{0.f, 0.f, 0.f, 0.f}};
#pragma unroll
            for (int ks = 0; ks < 4; ks++)
#pragma unroll
                for (int ct = 0; ct < 2; ct++)
                    acc[ct] = __builtin_amdgcn_mfma_f32_16x16x32_f16(ah[ks], wh[c][ct][ks], acc[ct], 0, 0, 0);
#pragma unroll
            for (int ct = 0; ct < 2; ct++) {
                int col = (wave * 2 + ct) * 16 + lr;
                float bcol = J.bias[c * 128 + col];
#pragma unroll
                for (int r = 0; r < 4; r++) {
                    int gr = crow0 + r;
                    if (gr < N) ys[c][(size_t)gr * 128 + col] = f2bf(acc[ct][r] + bcol);
                }
            }
        }
    }
}

// skip GEMM: single-plane f16 msg -> gated mix with single-plane f16 x (in place), 2 jobs
struct SJob { const u16* mhi; const u16* wh; const u16* wl;
              const float* bias; u16* xhi; const float* gate; int N; };
struct SJobs { SJob j[2]; };

__global__ __launch_bounds__(256, 4) void gemm_skip_k(SJobs jobs) {
    SJob J = jobs.j[blockIdx.y];
    int tid = threadIdx.x;
    int wave = tid >> 6, lane = tid & 63;
    int lr = lane & 15, kg = lane >> 4;

    half8 wh[2][4], wl[2][4];
#pragma unroll
    for (int ct = 0; ct < 2; ct++)
#pragma unroll
        for (int ks = 0; ks < 4; ks++) {
            int o = ((wave * 2 + ct) * 4 + ks) * 512 + kg * 128 + lr * 8;
            wh[ct][ks] = *(const half8*)(J.wh + o);
            wl[ct][ks] = *(const half8*)(J.wl + o);
        }
    float gk = J.gate[0];
    float g = 1.f / (1.f + __expf(-gk));
    float gi = 1.f - g;

    int ntiles = (J.N + 15) >> 4;
    for (int t = blockIdx.x; t < ntiles; t += gridDim.x) {
        int arow = t * 16 + lr;
        if (arow >= J.N) arow = J.N - 1;
        const u16* ph = J.mhi + (size_t)arow * 128 + kg * 8;
        half8 ah[4];
#pragma unroll
        for (int ks = 0; ks < 4; ks++) ah[ks] = *(const half8*)(ph + ks * 32);
        f32x4 acc[2] = {f32x4{0.f, 0.f, 0.f, 0.f}, f32x4{0.f, 0.f, 0.f, 0.f}};
#pragma unroll
        for (int ks = 0; ks < 4; ks++)
#pragma unroll
            for (int ct = 0; ct < 2; ct++) {
                acc[ct] = __builtin_amdgcn_mfma_f32_16x16x32_f16(ah[ks], wh[ct][ks], acc[ct], 0, 0, 0);
                acc[ct] = __builtin_amdgcn_mfma_f32_16x16x32_f16(ah[ks], wl[ct][ks], acc[ct], 0, 0, 0);
            }
        int crow0 = t * 16 + kg * 4;
#pragma unroll
        for (int ct = 0; ct < 2; ct++) {
            int col = (wave * 2 + ct) * 16 + lr;
            float bcol = J.bias[col];
#pragma unroll
            for (int r = 0; r < 4; r++) {
                int gr = crow0 + r;
                if (gr < J.N) {
                    size_t si = (size_t)gr * 128 + col;
                    float v = acc[ct][r] + bcol;
                    v = g * v + gi * h2f(J.xhi[si]);
                    J.xhi[si] = f2h(v);
                }
            }
        }
    }
}

// input projection: f32 A + relu -> single f16 plane, 2 jobs (value via full split math)
struct FJob { const float* x; const u16* wh; const u16* wl; const float* bias;
              u16* yhi; int N; };
struct FJobs { FJob j[2]; };

__global__ __launch_bounds__(256, 3) void gemm_in_k(FJobs jobs) {
    FJob J = jobs.j[blockIdx.y];
    int tid = threadIdx.x;
    int wave = tid >> 6, lane = tid & 63;
    int lr = lane & 15, kg = lane >> 4;

    half8 wh[2][4], wl[2][4];
#pragma unroll
    for (int ct = 0; ct < 2; ct++)
#pragma unroll
        for (int ks = 0; ks < 4; ks++) {
            int o = ((wave * 2 + ct) * 4 + ks) * 512 + kg * 128 + lr * 8;
            wh[ct][ks] = *(const half8*)(J.wh + o);
            wl[ct][ks] = *(const half8*)(J.wl + o);
        }

    int ntiles = (J.N + 15) >> 4;
    for (int t = blockIdx.x; t < ntiles; t += gridDim.x) {
        int arow = t * 16 + lr;
        if (arow >= J.N) arow = J.N - 1;
        const float* p = J.x + (size_t)arow * 128 + kg * 8;
        half8 ahi[4], alo[4];
#pragma unroll
        for (int ks = 0; ks < 4; ks++) {
            float4 v0 = *(const float4*)(p + ks * 32);
            float4 v1 = *(const float4*)(p + ks * 32 + 4);
            float a8[8] = {v0.x, v0.y, v0.z, v0.w, v1.x, v1.y, v1.z, v1.w};
#pragma unroll
            for (int j = 0; j < 8; j++) {
                _Float16 h = (_Float16)a8[j];
                ahi[ks][j] = h;
                alo[ks][j] = (_Float16)(a8[j] - (float)h);
            }
        }
        f32x4 acc[2] = {f32x4{0.f, 0.f, 0.f, 0.f}, f32x4{0.f, 0.f, 0.f, 0.f}};
#pragma unroll
        for (int ks = 0; ks < 4; ks++)
#pragma unroll
            for (int ct = 0; ct < 2; ct++) {
                acc[ct] = __builtin_amdgcn_mfma_f32_16x16x32_f16(ahi[ks], wh[ct][ks], acc[ct], 0, 0, 0);
                acc[ct] = __builtin_amdgcn_mfma_f32_16x16x32_f16(alo[ks], wh[ct][ks], acc[ct], 0, 0, 0);
                acc[ct] = __builtin_amdgcn_mfma_f32_16x16x32_f16(ahi[ks], wl[ct][ks], acc[ct], 0, 0, 0);
            }
        int crow0 = t * 16 + kg * 4;
#pragma unroll
        for (int ct = 0; ct < 2; ct++) {
            int col = (wave * 2 + ct) * 16 + lr;
            float bcol = J.bias[col];
#pragma unroll
            for (int r = 0; r < 4; r++) {
                int gr = crow0 + r;
                if (gr < J.N) {
                    float v = fmaxf(acc[ct][r] + bcol, 0.f);
                    J.yhi[(size_t)gr * 128 + col] = f2h(v);
                }
            }
        }
    }
}

// fused output: out = msg @ W1 + x @ W2 + bO   (f32 out, MOUT=64), 2 jobs
struct OJob { const u16* mhi; const u16* xhi;
              const u16* w1h; const u16* w1l; const u16* w2h; const u16* w2l;
              const float* bO; float* out; int N; };
struct OJobs { OJob j[2]; };

__global__ __launch_bounds__(256, 4) void gemm_out_k(OJobs jobs) {
    OJob J = jobs.j[blockIdx.y];
    int tid = threadIdx.x;
    int wave = tid >> 6, lane = tid & 63;
    int lr = lane & 15, kg = lane >> 4;

    half8 w1h[4], w1l[4], w2h[4], w2l[4];
#pragma unroll
    for (int ks = 0; ks < 4; ks++) {
        int o = (wave * 4 + ks) * 512 + kg * 128 + lr * 8;
        w1h[ks] = *(const half8*)(J.w1h + o);
        w1l[ks] = *(const half8*)(J.w1l + o);
        w2h[ks] = *(const half8*)(J.w2h + o);
        w2l[ks] = *(const half8*)(J.w2l + o);
    }

    int N = J.N;
    int ntiles = (N + 15) >> 4;
    for (int t = blockIdx.x; t < ntiles; t += gridDim.x) {
        int arow = t * 16 + lr;
        if (arow >= N) arow = N - 1;
        const u16* pm = J.mhi + (size_t)arow * 128 + kg * 8;
        const u16* px = J.xhi + (size_t)arow * 128 + kg * 8;
        half8 am[4], ax[4];
#pragma unroll
        for (int ks = 0; ks < 4; ks++) {
            am[ks] = *(const half8*)(pm + ks * 32);
            ax[ks] = *(const half8*)(px + ks * 32);
        }
        f32x4 acc = f32x4{0.f, 0.f, 0.f, 0.f};
#pragma unroll
        for (int ks = 0; ks < 4; ks++) {
            acc = __builtin_amdgcn_mfma_f32_16x16x32_f16(am[ks], w1h[ks], acc, 0, 0, 0);
            acc = __builtin_amdgcn_mfma_f32_16x16x32_f16(am[ks], w1l[ks], acc, 0, 0, 0);
            acc = __builtin_amdgcn_mfma_f32_16x16x32_f16(ax[ks], w2h[ks], acc, 0, 0, 0);
            acc = __builtin_amdgcn_mfma_f32_16x16x32_f16(ax[ks], w2l[ks], acc, 0, 0, 0);
        }
        int crow0 = t * 16 + kg * 4;
        int col = wave * 16 + lr;
        float bcol = J.bO[col];
#pragma unroll
        for (int r = 0; r < 4; r++) {
            int gr = crow0 + r;
            if (gr < N) J.out[(size_t)gr * 64 + col] = acc[r] + bcol;
        }
    }
}

// ---------- launch ----------
extern "C" void kernel_launch(void* const* d_in, const int* in_sizes, int n_in,
                              void* d_out, int out_size, void* d_ws, size_t ws_size,
                              hipStream_t stream) {
    const int NQ = in_sizes[0] / 128;
    const int NA = in_sizes[1] / 128;
    const int Eqa = in_sizes[29] / 2;
    const int Eaq = in_sizes[30] / 2;
    const int NM = (NQ > NA) ? NQ : NA;
    const int EM = (Eqa > Eaq) ? Eqa : Eaq;

    const float* x_q     = (const float*)d_in[0];
    const float* x_a     = (const float*)d_in[1];
    const float* lin0_wq = (const float*)d_in[2];
    const float* lin0_bq = (const float*)d_in[3];
    const float* lin0_wa = (const float*)d_in[4];
    const float* lin0_ba = (const float*)d_in[5];
    const float* kw_q = (const float*)d_in[6];
    const float* kb_q = (const float*)d_in[7];
    const float* qw_q = (const float*)d_in[8];
    const float* qb_q = (const float*)d_in[9];
    const float* vw_q = (const float*)d_in[10];
    const float* vb_q = (const float*)d_in[11];
    const float* aw_q = (const float*)d_in[12];
    const float* ab_q = (const float*)d_in[13];
    const float* kw_a = (const float*)d_in[14];
    const float* kb_a = (const float*)d_in[15];
    const float* qw_a = (const float*)d_in[16];
    const float* qb_a = (const float*)d_in[17];
    const float* vw_a = (const float*)d_in[18];
    const float* vb_a = (const float*)d_in[19];
    const float* aw_a = (const float*)d_in[20];
    const float* ab_a = (const float*)d_in[21];
    const float* skip_q = (const float*)d_in[22];
    const float* skip_a = (const float*)d_in[23];
    const float* a_rel = (const float*)d_in[24];
    const float* m_rel = (const float*)d_in[25];
    const float* p_rel = (const float*)d_in[26];
    const float* lin_w = (const float*)d_in[27];
    const float* lin_b = (const float*)d_in[28];
    const int* ei_qa = (const int*)d_in[29];
    const int* ei_aq = (const int*)d_in[30];

    // ---- workspace ----
    size_t off = 0;
    auto alloc = [&](size_t bytes) -> void* {
        void* p = (char*)d_ws + off;
        off += (bytes + 255) & ~(size_t)255;
        return p;
    };
    u16* xhi = (u16*)alloc((size_t)(NQ + NA) * 128 * 2);   // rows [0,NQ)=q, rest=a
    u16* xq_hi = xhi;
    u16* xa_hi = xhi + (size_t)NQ * 128;
    u16* mq_hi = (u16*)alloc((size_t)NQ * 128 * 2);
    u16* ma_hi = (u16*)alloc((size_t)NA * 128 * 2);
    u16* kt0 = (u16*)alloc((size_t)NM * 128 * 2);
    u16* vt0 = (u16*)alloc((size_t)NM * 128 * 2);
    u16* qdq = (u16*)alloc((size_t)NM * 128 * 2);
    u16* kt1 = (u16*)alloc((size_t)NM * 128 * 2);
    u16* vt1 = (u16*)alloc((size_t)NM * 128 * 2);
    u16* qda = (u16*)alloc((size_t)NM * 128 * 2);
    int* offs_a = (int*)alloc((size_t)(NA + 1) * 4);
    int* offs_q = (int*)alloc((size_t)(NQ + 1) * 4);
    int* srcc_a = (int*)alloc((size_t)Eqa * 4);
    int* srcc_q = (int*)alloc((size_t)Eaq * 4);
    int* deg    = (int*)alloc((size_t)2 * NM * 4);
    int* cursor = (int*)alloc((size_t)2 * NM * 4);
    int* incl   = (int*)alloc((size_t)2 * NM * 4);
    int* bsum   = (int*)alloc(2048);
    u16* W_LIN0Q_h = (u16*)alloc(16384 * 2); u16* W_LIN0Q_l = (u16*)alloc(16384 * 2);
    u16* W_LIN0A_h = (u16*)alloc(16384 * 2); u16* W_LIN0A_l = (u16*)alloc(16384 * 2);
    u16* WQ_h = (u16*)alloc(2 * 3 * 16384 * 2); u16* WQ_l = (u16*)alloc(2 * 3 * 16384 * 2);
    u16* WA_h = (u16*)alloc(2 * 3 * 16384 * 2); u16* WA_l = (u16*)alloc(2 * 3 * 16384 * 2);
    u16* W_AQ_h = (u16*)alloc(2 * 16384 * 2); u16* W_AQ_l = (u16*)alloc(2 * 16384 * 2);
    u16* W_AA_h = (u16*)alloc(2 * 16384 * 2); u16* W_AA_l = (u16*)alloc(2 * 16384 * 2);
    u16* W1h = (u16*)alloc(2 * 8192 * 2); u16* W1l = (u16*)alloc(2 * 8192 * 2);
    u16* W2h = (u16*)alloc(2 * 8192 * 2); u16* W2l = (u16*)alloc(2 * 8192 * 2);
    float* bO = (float*)alloc(2 * 64 * 4);
    float* BQ = (float*)alloc(2 * 384 * 4);
    float* BA = (float*)alloc(2 * 384 * 4);
    (void)ws_size; (void)n_in; (void)out_size; (void)EM;

    dim3 B(256);

    // merged weight prep (transpose + fused rel in one dispatch)
    PrepArgs pa;
    pa.j[0]  = {lin0_wq, W_LIN0Q_h, W_LIN0Q_l, 128};
    pa.j[1]  = {lin0_wa, W_LIN0A_h, W_LIN0A_l, 128};
    pa.j[2]  = {qw_q,          WQ_h + (0 * 3 + 2) * 16384, WQ_l + (0 * 3 + 2) * 16384, 128};
    pa.j[3]  = {qw_q + 16384,  WQ_h + (1 * 3 + 2) * 16384, WQ_l + (1 * 3 + 2) * 16384, 128};
    pa.j[4]  = {qw_a,          WA_h + (0 * 3 + 2) * 16384, WA_l + (0 * 3 + 2) * 16384, 128};
    pa.j[5]  = {qw_a + 16384,  WA_h + (1 * 3 + 2) * 16384, WA_l + (1 * 3 + 2) * 16384, 128};
    pa.j[6]  = {aw_q,          W_AQ_h,            W_AQ_l,            128};
    pa.j[7]  = {aw_q + 16384,  W_AQ_h + 16384,    W_AQ_l + 16384,    128};
    pa.j[8]  = {aw_a,          W_AA_h,            W_AA_l,            128};
    pa.j[9]  = {aw_a + 16384,  W_AA_h + 16384,    W_AA_l + 16384,    128};
    pa.kw_q = kw_q; pa.kw_a = kw_a; pa.vw_q = vw_q; pa.vw_a = vw_a;
    pa.a_rel = a_rel; pa.m_rel = m_rel;
    pa.WQh = WQ_h; pa.WQl = WQ_l; pa.WAh = WA_h; pa.WAl = WA_l;
    prep_all_k<<<dim3(64, 18), B, 0, stream>>>(pa);
    prep_bias_k<<<dim3(6), B, 0, stream>>>(kb_q, vb_q, qb_q, kb_a, vb_a, qb_a,
                                           a_rel, m_rel, BQ, BA);
    prep_out_k<<<dim3(32, 2), B, 0, stream>>>(aw_q, ab_q, skip_q, aw_a, ab_a, skip_a,
                                              lin_w, lin_b, W1h, W1l, W2h, W2l, bO);

    // CSR build
    int* degA = deg;        int* degB = deg + NM;
    int* curA = cursor;     int* curB = cursor + NM;
    int* incA = incl;       int* incB = incl + NM;
    int* bsA  = bsum;       int* bsB  = bsum + 256;
    int gEm = (EM + 255) / 256, gNm = (NM + 255) / 256;
    int gNa = (NA + 255) / 256, gNq = (NQ + 255) / 256;
    hipMemsetAsync(deg, 0, (size_t)2 * NM * 4, stream);
    hist2_k<<<dim3(gEm, 2), B, 0, stream>>>(ei_qa + Eqa, Eqa, degA, ei_aq + Eaq, Eaq, degB);
    scanA2_k<<<dim3(gNm, 2), B, 0, stream>>>(degA, incA, bsA, NA, degB, incB, bsB, NQ);
    scanB2_k<<<dim3(2), B, 0, stream>>>(bsA, gNa, bsB, gNq);
    scanC2_k<<<dim3(gNm, 2), B, 0, stream>>>(incA, degA, bsA, offs_a, curA, NA, Eqa,
                                             incB, degB, bsB, offs_q, curB, NQ, Eaq);
    scatter2_k<<<dim3(gEm, 2), B, 0, stream>>>(ei_qa, Eqa, curA, srcc_a,
                                               ei_aq, Eaq, curB, srcc_q);

    // input projections + relu -> single f16 plane (one dispatch, 2 jobs)
    {
        FJobs fj;
        fj.j[0] = {x_q, W_LIN0Q_h, W_LIN0Q_l, lin0_bq, xq_hi, NQ};
        fj.j[1] = {x_a, W_LIN0A_h, W_LIN0A_l, lin0_ba, xa_hi, NA};
        gemm_in_k<<<dim3(1024, 2), B, 0, stream>>>(fj);
    }

    for (int l = 0; l < 2; l++) {
        // per side: one job computes kt|vt|qd (A read once, 3 W slices)
        GJobs3 gj;
        gj.j[0] = {xq_hi, WQ_h + l * 3 * 16384, BQ + l * 384, kt0, vt0, qdq, NQ};
        gj.j[1] = {xa_hi, WA_h + l * 3 * 16384, BA + l * 384, kt1, vt1, qda, NA};
        gemm_proj3_k<<<dim3(1024, 2), B, 0, stream>>>(gj);

        // both edge directions in one dispatch (bf16 kt/vt/qd -> single f16 msg plane)
        EJobs ej;
        ej.j[0] = {offs_a, srcc_a, kt0, vt0, qda, p_rel + (l * 2 + 0) * 8, ma_hi, NA};
        ej.j[1] = {offs_q, srcc_q, kt1, vt1, qdq, p_rel + (l * 2 + 1) * 8, mq_hi, NQ};
        edge_fused_k<<<dim3((NM + 3) / 4, 2), B, 0, stream>>>(ej);

        if (l == 0) {
            // layer-0 skip (in-place on single x plane)
            SJobs sj;
            sj.j[0] = {mq_hi, W_AQ_h, W_AQ_l, ab_q, xq_hi, skip_q, NQ};
            sj.j[1] = {ma_hi, W_AA_h, W_AA_l, ab_a, xa_hi, skip_a, NA};
            gemm_skip_k<<<dim3(1024, 2), B, 0, stream>>>(sj);
        } else {
            // layer-1 skip folded into final linear: out = msg@W1 + x1@W2 + bO
            OJobs oj;
            oj.j[0] = {mq_hi, xq_hi, W1h, W1l, W2h, W2l, bO,
                       (float*)d_out, NQ};
            oj.j[1] = {ma_hi, xa_hi, W1h + 8192, W1l + 8192, W2h + 8192, W2l + 8192, bO + 64,
                       (float*)d_out + (size_t)NQ * 64, NA};
            gemm_out_k<<<dim3(1024, 2), B, 0, stream>>>(oj);
        }
    }
}